// Round 6
// baseline (424.340 us; speedup 1.0000x reference)
//
#include <hip/hip_runtime.h>
#include <stdint.h>

typedef unsigned short u16;
typedef __attribute__((ext_vector_type(4))) float    floatx4;
typedef __attribute__((ext_vector_type(8))) __bf16   bf16x8;
typedef __attribute__((ext_vector_type(2))) unsigned int uintx2;
typedef __attribute__((ext_vector_type(4))) unsigned int uintx4;

__device__ inline u16 f2bf(float f) {            // RNE float->bf16
  unsigned int u = __builtin_bit_cast(unsigned int, f);
  u += 0x7fffu + ((u >> 16) & 1u);
  return (u16)(u >> 16);
}

#define GLD16(gsrc, ldst)                                                        \
  __builtin_amdgcn_global_load_lds(                                              \
      (__attribute__((address_space(1))) void*)(gsrc),                           \
      (__attribute__((address_space(3))) void*)(ldst), 16, 0, 0)

#define SB() __builtin_amdgcn_sched_barrier(0)

// ---------------------------------------------------------------------------
// combined prep: z<3 -> transpose-cast W_z into WT; z>=3 -> cast x -> bf16
__global__ __launch_bounds__(256) void prep_kernel(const float* __restrict__ x,
                                                   const float* __restrict__ Wq,
                                                   const float* __restrict__ Wk,
                                                   const float* __restrict__ Wv,
                                                   u16* __restrict__ xb,
                                                   u16* __restrict__ WT) {
  const int z = blockIdx.z;
  const int tid = threadIdx.y * 32 + threadIdx.x;
  if (z >= 3) {   // cast x chunk
    long blk = (long)(z - 3) * 1024 + blockIdx.y * 32 + blockIdx.x;
    long i = (blk * 256 + tid) * 8;
    floatx4 a = *(const floatx4*)(x + i);
    floatx4 b = *(const floatx4*)(x + i + 4);
    uintx4 o;
    o[0] = (unsigned)f2bf(a[0]) | ((unsigned)f2bf(a[1]) << 16);
    o[1] = (unsigned)f2bf(a[2]) | ((unsigned)f2bf(a[3]) << 16);
    o[2] = (unsigned)f2bf(b[0]) | ((unsigned)f2bf(b[1]) << 16);
    o[3] = (unsigned)f2bf(b[2]) | ((unsigned)f2bf(b[3]) << 16);
    *(uintx4*)(xb + i) = o;
    return;
  }
  __shared__ float tile[32][33];
  const float* W = (z == 0) ? Wq : (z == 1) ? Wk : Wv;
  u16* dst = WT + (long)z * 1024 * 1024;
  int bx = blockIdx.x * 32, by = blockIdx.y * 32;
  int tx = threadIdx.x, ty = threadIdx.y;                 // 32 x 8
  for (int i = 0; i < 32; i += 8)
    tile[ty + i][tx] = W[(long)(by + ty + i) * 1024 + bx + tx];
  __syncthreads();
  for (int i = 0; i < 32; i += 8)
    dst[(long)(bx + ty + i) * 1024 + by + tx] = f2bf(tile[tx][ty + i]);
}

// ---------------------------------------------------------------------------
// gemm_bt: C[m][n] = sum_k A[m][k] * Bt[n][k]   (A, Bt bf16, lda=ldb=K)
// OCCUPANCY ROUND: 128x128 tile, BK=64, 512 threads = 8 waves (2M x 4N),
// per-wave 64x32 (acc[4][2] = 32 AGPR). LDS 64 KiB -> 2 blocks/CU,
// 4 waves/SIMD: two INDEPENDENT barrier groups per CU fill each other's
// vmcnt/barrier/DMA stalls (m114 mechanism). Per-CU per-K-tile LDS-read /
// MFMA / DMA loads are IDENTICAL to the 256x256 1-block config — the only
// change is barrier topology. r1-r5 showed schedule shape is flat at
// 1 block/CU; this isolates occupancy.
// Schedule (2 phases/K-tile, correct-by-construction):
//  ph0(t): ds_read ks0; stage ALL 4 units(t+1)->nxt; barrier; lgkm(0);
//          setprio 8 MFMA.
//  ph1(t): ds_read ks1; vmcnt(0) [forces t+1, issued ~800cy earlier; residual
//          stall filled by co-resident block]; barrier; lgkm(0); 8 MFMA.
// Swizzle: row = 64 u16 = 8 chunks; LDS slot sc holds source chunk sc^(r&7)
// (identical 0-conflict formula as prior rounds; rule #21 both-sides pair).
// MODE 0: merged q|k projection; MODE 1: vT scatter; MODE 2: exp+rowsum;
// MODE 3: fp32 / lsum[row].
#define BM 128
#define BN 128
#define BK 64

template <int MODE, int GN>
__global__ __launch_bounds__(512, 4)
void gemm_bt(const u16* __restrict__ Aall, const u16* __restrict__ Ball,
             void* __restrict__ Call, void* __restrict__ C2,
             const float* __restrict__ bias, const float* __restrict__ bias2,
             float* __restrict__ lsum,
             int M, int N, int K, long aStride, long bStride, long cStride) {
  __shared__ __align__(16) u16 As[2][BM * BK];   // 2 x 16 KB
  __shared__ __align__(16) u16 Bs[2][BN * BK];   // 2 x 16 KB

  const int z = blockIdx.z;
  const u16* A  = Aall + (long)z * aStride;
  const u16* Bt = Ball + (long)z * bStride;

  // XCD-chunked bijective swizzle, then GN grouping
  int m_idx, n_idx;
  {
    const int tiles_n = gridDim.x, tiles_m = gridDim.y;
    int nwg = tiles_n * tiles_m;
    int bid = blockIdx.y * tiles_n + blockIdx.x;
    int qq = nwg >> 3;                       // all grids are %8 == 0
    int L = (bid & 7) * qq + (bid >> 3);
    int per_group = GN * tiles_m;
    int g = L / per_group;
    int rem = L - g * per_group;
    n_idx = g * GN + rem % GN;
    m_idx = rem / GN;
  }

  const int tid  = threadIdx.x;
  const int m0   = m_idx * BM;
  const int n0   = n_idx * BN;
  const int wave = tid >> 6;
  const int lane = tid & 63;
  const int wm   = (wave >> 2) * 64;     // wave row offset (2 waves in M)
  const int wn   = (wave & 3) * 32;      // wave col offset (4 waves in N)
  const int l15  = lane & 15;
  const int quad = lane >> 4;

  floatx4 acc[4][2];
  floatx4 zero = {0.f, 0.f, 0.f, 0.f};
#pragma unroll
  for (int i = 0; i < 4; ++i)
#pragma unroll
    for (int j = 0; j < 2; ++j) acc[i][j] = zero;

  // LDS read offsets (u16), loop-invariant. slot = (ks*4+quad)^(r&7),
  // r&7 == l15&7 (wm,wn,mi*16 all 0 mod 8); ks1 = ks0 ^ 32 (u16).
  const int swz   = (quad ^ (l15 & 7)) * 8;
  const int aOff0 = (wm + l15) * 64 + swz;
  const int bOff0 = (wn + l15) * 64 + swz;

  // staging: unit u (A0,A1,B0,B1), chunk ci = u*512+tid -> row r=ci>>3,
  // slot sc=ci&7 holds source k-chunk sc^(r&7) (source-swizzle, rule #21).
  const u16* gA[2];
  const u16* gB[2];
#pragma unroll
  for (int i = 0; i < 2; ++i) {
    int ci = i * 512 + tid;
    int r = ci >> 3, sc = ci & 7;
    int col = (sc ^ (r & 7)) * 8;
    gA[i] = A  + (long)(m0 + r) * K + col;
    gB[i] = Bt + (long)(n0 + r) * K + col;
  }

  const int nt = K / BK;            // 16 or 32 here

  // prologue: tile 0 (4 units), drain, barrier
  {
    u16* lA = (u16*)As + tid * 8;
    u16* lB = (u16*)Bs + tid * 8;
    GLD16(gA[0], lA); GLD16(gA[1], lA + 4096);
    GLD16(gB[0], lB); GLD16(gB[1], lB + 4096);
  }
  SB();
  asm volatile("s_waitcnt vmcnt(0)" ::: "memory");
  SB();
  __builtin_amdgcn_s_barrier();
  SB();
#pragma unroll
  for (int i = 0; i < 2; ++i) { gA[i] += BK; gB[i] += BK; }

  for (int t = 0; t < nt; ++t) {
    const int cur = t & 1;
    const int bo  = cur << 13;                       // cur * 8192 u16 (16 KB)
    const u16* aP0 = (const u16*)As + bo + aOff0;    // ks0 base
    const u16* bP0 = (const u16*)Bs + bo + bOff0;
    const u16* aP1 = (const u16*)As + bo + (aOff0 ^ 32);   // ks1 base
    const u16* bP1 = (const u16*)Bs + bo + (bOff0 ^ 32);
    u16* ldsAn = (u16*)As + (bo ^ 8192) + tid * 8;   // next-buffer dests
    u16* ldsBn = (u16*)Bs + (bo ^ 8192) + tid * 8;
    const bool st1 = (t + 1 < nt);
    bf16x8 af[4], bfr[2];

    // ================= phase 0: ks0 =================
#pragma unroll
    for (int mi = 0; mi < 4; ++mi)
      af[mi] = *(const bf16x8*)(aP0 + mi * 1024);
#pragma unroll
    for (int ni = 0; ni < 2; ++ni)
      bfr[ni] = *(const bf16x8*)(bP0 + ni * 1024);
    if (st1) {
      GLD16(gA[0], ldsAn); GLD16(gA[1], ldsAn + 4096);
      GLD16(gB[0], ldsBn); GLD16(gB[1], ldsBn + 4096);
    }
    SB();
    __builtin_amdgcn_s_barrier();
    asm volatile("s_waitcnt lgkmcnt(0)" ::: "memory");
    SB();
    __builtin_amdgcn_s_setprio(1);
#pragma unroll
    for (int mi = 0; mi < 4; ++mi)
#pragma unroll
      for (int ni = 0; ni < 2; ++ni)
        acc[mi][ni] = __builtin_amdgcn_mfma_f32_16x16x32_bf16(
            bfr[ni], af[mi], acc[mi][ni], 0, 0, 0);   // swapped operands
    __builtin_amdgcn_s_setprio(0);
    SB();

    // ================= phase 1: ks1 =================
#pragma unroll
    for (int mi = 0; mi < 4; ++mi)
      af[mi] = *(const bf16x8*)(aP1 + mi * 1024);
#pragma unroll
    for (int ni = 0; ni < 2; ++ni)
      bfr[ni] = *(const bf16x8*)(bP1 + ni * 1024);
    SB();
    // force tile t+1 landed (issued one phase ago) before the barrier that
    // precedes ph0(t+1)'s reads; co-resident block fills any residual wait
    asm volatile("s_waitcnt vmcnt(0)" ::: "memory");
    SB();
    __builtin_amdgcn_s_barrier();
    asm volatile("s_waitcnt lgkmcnt(0)" ::: "memory");
    SB();
    __builtin_amdgcn_s_setprio(1);
#pragma unroll
    for (int mi = 0; mi < 4; ++mi)
#pragma unroll
      for (int ni = 0; ni < 2; ++ni)
        acc[mi][ni] = __builtin_amdgcn_mfma_f32_16x16x32_bf16(
            bfr[ni], af[mi], acc[mi][ni], 0, 0, 0);
    __builtin_amdgcn_s_setprio(0);
    SB();

#pragma unroll
    for (int i = 0; i < 2; ++i) { gA[i] += BK; gB[i] += BK; }
  }

  // epilogue (swapped D layout): row(m) = l15-based, 4 regs = 4 consecutive n-cols
#pragma unroll
  for (int mi = 0; mi < 4; ++mi) {
    const int row = m0 + wm + mi * 16 + l15;      // fixed per lane
    if (MODE == 2) {
      u16* C = (u16*)Call + (long)z * cStride;
      float rs = 0.f;
#pragma unroll
      for (int ni = 0; ni < 2; ++ni) {
        int colb = n0 + wn + ni * 16 + quad * 4;
        floatx4 v = acc[mi][ni];
        float e0 = __expf(v[0] * 0.03125f), e1 = __expf(v[1] * 0.03125f);
        float e2 = __expf(v[2] * 0.03125f), e3 = __expf(v[3] * 0.03125f);
        rs += (e0 + e1) + (e2 + e3);
        uintx2 o;
        o[0] = (unsigned)f2bf(e0) | ((unsigned)f2bf(e1) << 16);
        o[1] = (unsigned)f2bf(e2) | ((unsigned)f2bf(e3) << 16);
        *(uintx2*)(C + (long)row * N + colb) = o;
      }
      rs += __shfl_xor(rs, 16);
      rs += __shfl_xor(rs, 32);
      if (quad == 0) atomicAdd(lsum + (long)z * 2048 + row, rs);
    } else if (MODE == 3) {
      float* C = (float*)Call + (long)z * cStride;
      float inv = 1.0f / lsum[(long)z * 2048 + row];
#pragma unroll
      for (int ni = 0; ni < 2; ++ni) {
        int colb = n0 + wn + ni * 16 + quad * 4;
        floatx4 v = acc[mi][ni];
        floatx4 o = {v[0] * inv, v[1] * inv, v[2] * inv, v[3] * inv};
        *(floatx4*)(C + (long)row * N + colb) = o;
      }
    } else if (MODE == 0) {
#pragma unroll
      for (int ni = 0; ni < 2; ++ni) {
        int colb = n0 + wn + ni * 16 + quad * 4;
        u16* C = (colb < 1024) ? (u16*)Call : (u16*)C2;
        const float* bp = (colb < 1024) ? bias + colb : bias2 + (colb - 1024);
        floatx4 b = *(const floatx4*)bp;
        floatx4 v = acc[mi][ni];
        uintx2 o;
        o[0] = (unsigned)f2bf(v[0] + b[0]) | ((unsigned)f2bf(v[1] + b[1]) << 16);
        o[1] = (unsigned)f2bf(v[2] + b[2]) | ((unsigned)f2bf(v[3] + b[3]) << 16);
        *(uintx2*)(C + (long)row * 1024 + (colb & 1023)) = o;
      }
    } else {  // MODE 1: vT scatter — row=do, cols=4 consecutive t
      u16* C = (u16*)Call;
      float b = bias[row];
#pragma unroll
      for (int ni = 0; ni < 2; ++ni) {
        int colb = n0 + wn + ni * 16 + quad * 4;   // global t index over B*T
        long base = ((long)(colb >> 11) * 1024) * 2048 + (colb & 2047);
        floatx4 v = acc[mi][ni];
        uintx2 o;
        o[0] = (unsigned)f2bf(v[0] + b) | ((unsigned)f2bf(v[1] + b) << 16);
        o[1] = (unsigned)f2bf(v[2] + b) | ((unsigned)f2bf(v[3] + b) << 16);
        *(uintx2*)(C + base + (long)row * 2048) = o;
      }
    }
  }
}

// ---------------------------------------------------------------------------
extern "C" void kernel_launch(void* const* d_in, const int* in_sizes, int n_in,
                              void* d_out, int out_size, void* d_ws, size_t ws_size,
                              hipStream_t stream) {
  const float* x  = (const float*)d_in[0];
  const float* Wq = (const float*)d_in[1];
  const float* bq = (const float*)d_in[2];
  const float* Wk = (const float*)d_in[3];
  const float* bk = (const float*)d_in[4];
  const float* Wv = (const float*)d_in[5];
  const float* bv = (const float*)d_in[6];
  float* out = (float*)d_out;

  const long BT = 16384;   // B*T
  u16* xb = (u16*)d_ws;                    // [16384,1024] bf16   32 MB
  u16* WT = xb + BT * 1024;                // [3][1024,1024]       6 MB
  u16* qb = WT + 3L * 1024 * 1024;         // [16384,1024]        32 MB
  u16* kb = qb + BT * 1024;                // [16384,1024]        32 MB
  u16* vT = kb + BT * 1024;                // [8][1024][2048]     32 MB
  u16* S  = vT + BT * 1024;                // [8][2048][2048]     64 MB
  float* lsum = (float*)(S + 8L * 2048 * 2048);   // [8][2048]    64 KB

  hipMemsetAsync(lsum, 0, 8 * 2048 * sizeof(float), stream);

  // z 0..2: transpose-cast W; z 3..10: cast x
  prep_kernel<<<dim3(32, 32, 11), dim3(32, 8), 0, stream>>>(x, Wq, Wk, Wv, xb, WT);

  // q|k = x [Wq|Wk] + [bq|bk]   (WT rows 0..2047 are Wq^T then Wk^T)
  gemm_bt<0, 8><<<dim3(16, 128, 1), 512, 0, stream>>>(
      xb, WT, qb, kb, bq, bk, nullptr, 16384, 2048, 1024, 0, 0, 0);
  // vT[b][do][t] = (Wv^T x^T + bv) : A=WvT [1024,1024], Bt=xb [16384,1024]
  gemm_bt<1, 8><<<dim3(128, 8, 1), 512, 0, stream>>>(
      WT + 2L * 1024 * 1024, xb, vT, nullptr, bv, nullptr, nullptr,
      1024, 16384, 1024, 0, 0, 0);
  // E[b] = exp(q_b k_b^T / 32), row-sums -> lsum
  gemm_bt<2, 8><<<dim3(16, 16, 8), 512, 0, stream>>>(
      qb, kb, S, nullptr, nullptr, nullptr, lsum,
      2048, 2048, 1024, 2048L * 1024, 2048L * 1024, 2048L * 2048);
  // out[b] = (E_b V_b) / lsum : A=E [2048,2048], Bt=vT_b [1024,2048]
  gemm_bt<3, 4><<<dim3(8, 16, 8), 512, 0, stream>>>(
      S, vT, out, nullptr, nullptr, nullptr, lsum,
      2048, 1024, 2048, 2048L * 2048, 1024L * 2048, 2048L * 1024);
}

// Round 7
// 400.478 us; speedup vs baseline: 1.0596x; 1.0596x over previous
//
#include <hip/hip_runtime.h>
#include <stdint.h>

typedef unsigned short u16;
typedef __attribute__((ext_vector_type(4))) float    floatx4;
typedef __attribute__((ext_vector_type(8))) __bf16   bf16x8;
typedef __attribute__((ext_vector_type(2))) unsigned int uintx2;
typedef __attribute__((ext_vector_type(4))) unsigned int uintx4;

__device__ inline u16 f2bf(float f) {            // RNE float->bf16
  unsigned int u = __builtin_bit_cast(unsigned int, f);
  u += 0x7fffu + ((u >> 16) & 1u);
  return (u16)(u >> 16);
}

#define GLD16(gsrc, ldst)                                                        \
  __builtin_amdgcn_global_load_lds(                                              \
      (__attribute__((address_space(1))) void*)(gsrc),                           \
      (__attribute__((address_space(3))) void*)(ldst), 16, 0, 0)

#define SB() __builtin_amdgcn_sched_barrier(0)

// ---------------------------------------------------------------------------
// combined prep: z<3 -> transpose-cast W_z into WT; z>=3 -> cast x -> bf16
__global__ __launch_bounds__(256) void prep_kernel(const float* __restrict__ x,
                                                   const float* __restrict__ Wq,
                                                   const float* __restrict__ Wk,
                                                   const float* __restrict__ Wv,
                                                   u16* __restrict__ xb,
                                                   u16* __restrict__ WT) {
  const int z = blockIdx.z;
  const int tid = threadIdx.y * 32 + threadIdx.x;
  if (z >= 3) {   // cast x chunk
    long blk = (long)(z - 3) * 1024 + blockIdx.y * 32 + blockIdx.x;
    long i = (blk * 256 + tid) * 8;
    floatx4 a = *(const floatx4*)(x + i);
    floatx4 b = *(const floatx4*)(x + i + 4);
    uintx4 o;
    o[0] = (unsigned)f2bf(a[0]) | ((unsigned)f2bf(a[1]) << 16);
    o[1] = (unsigned)f2bf(a[2]) | ((unsigned)f2bf(a[3]) << 16);
    o[2] = (unsigned)f2bf(b[0]) | ((unsigned)f2bf(b[1]) << 16);
    o[3] = (unsigned)f2bf(b[2]) | ((unsigned)f2bf(b[3]) << 16);
    *(uintx4*)(xb + i) = o;
    return;
  }
  __shared__ float tile[32][33];
  const float* W = (z == 0) ? Wq : (z == 1) ? Wk : Wv;
  u16* dst = WT + (long)z * 1024 * 1024;
  int bx = blockIdx.x * 32, by = blockIdx.y * 32;
  int tx = threadIdx.x, ty = threadIdx.y;                 // 32 x 8
  for (int i = 0; i < 32; i += 8)
    tile[ty + i][tx] = W[(long)(by + ty + i) * 1024 + bx + tx];
  __syncthreads();
  for (int i = 0; i < 32; i += 8)
    dst[(long)(bx + ty + i) * 1024 + by + tx] = f2bf(tile[tx][ty + i]);
}

// ---------------------------------------------------------------------------
// gemm_bt: C[m][n] = sum_k A[m][k] * Bt[n][k]   (A, Bt bf16, lda=ldb=K)
// 256x256 tile, BK=64, 512 threads = 8 waves (2M x 4N), per-wave 128x64.
// FAITHFUL m201 phase structure (finally): 4 phases/K-tile, each phase =
// one 32-ROW slice of the wave's accumulator x FULL K=64 ("one C-quadrant
// x K=64").  B fragments (8 x b128) are loaded ONCE per K-tile in ph0 and
// HELD IN REGISTERS across all 4 phases; ph0 = 12 ds_reads (+lgkmcnt(8)
// pre-barrier hint, per template), ph1-3 = 4 ds_reads each.  Each phase:
// { ds_reads | 2 global_load_lds | counted vmcnt | BAR | lgkm(0) |
//   setprio 16 MFMA setprio | BAR }  (double barrier, template-exact).
// Stage (tile t+1 -> buf c^1): ph0:Bh0 ph1:Bh1 ph2:Ah0 ph3:Ah1 (halves =
// 128-row bands = r4's unit pairs).  vmcnt ledger (2 insts/stage):
//   ph3(t): issue Ah1(t+1), outstanding 8 -> vmcnt(2) forces Bh0,Bh1,Ah0(t+1)
//           [needed by ph0/ph1(t+1); B read only in ph0].
//   ph1(t): outstanding Ah1(t)+Bh0,Bh1(t+1) = 6 -> vmcnt(4) forces Ah1(t)
//           [needed by ph2(t); staged ph3(t-1), 2 phases in flight].
//   last tile (no stages): vmcnt(0) at ph1 (loads long landed, free).
// Overwrite safety: every DMA target's last reads are >=3 barriers upstream.
// Addressing/swizzle identical to r4 (0 conflicts, verified).
// MODE 0: merged q|k projection; MODE 1: vT scatter; MODE 2: exp+rowsum;
// MODE 3: fp32 / lsum[row].
#define BM 256
#define BN 256
#define BK 64

template <int MODE, int GN>
__global__ __launch_bounds__(512, 2)
void gemm_bt(const u16* __restrict__ Aall, const u16* __restrict__ Ball,
             void* __restrict__ Call, void* __restrict__ C2,
             const float* __restrict__ bias, const float* __restrict__ bias2,
             float* __restrict__ lsum,
             int M, int N, int K, long aStride, long bStride, long cStride) {
  __shared__ __align__(16) u16 As[2][BM * BK];   // 2 x 32 KB
  __shared__ __align__(16) u16 Bs[2][BN * BK];   // 2 x 32 KB

  const int z = blockIdx.z;
  const u16* A  = Aall + (long)z * aStride;
  const u16* Bt = Ball + (long)z * bStride;

  // XCD-chunked bijective swizzle, then GN grouping
  int m_idx, n_idx;
  {
    const int tiles_n = gridDim.x, tiles_m = gridDim.y;
    int nwg = tiles_n * tiles_m;
    int bid = blockIdx.y * tiles_n + blockIdx.x;
    int qq = nwg >> 3;                       // all grids are %8 == 0
    int L = (bid & 7) * qq + (bid >> 3);
    int per_group = GN * tiles_m;
    int g = L / per_group;
    int rem = L - g * per_group;
    n_idx = g * GN + rem % GN;
    m_idx = rem / GN;
  }

  const int tid  = threadIdx.x;
  const int m0   = m_idx * BM;
  const int n0   = n_idx * BN;
  const int wave = tid >> 6;
  const int lane = tid & 63;
  const int wm   = (wave >> 2) * 128;    // wave row offset (2 waves in M)
  const int wn   = (wave & 3) * 64;      // wave col offset (4 waves in N)
  const int l15  = lane & 15;
  const int quad = lane >> 4;

  floatx4 acc[8][4];
  floatx4 zero = {0.f, 0.f, 0.f, 0.f};
#pragma unroll
  for (int i = 0; i < 8; ++i)
#pragma unroll
    for (int j = 0; j < 4; ++j) acc[i][j] = zero;

  // LDS read offsets (u16), loop-invariant. slot = (ks*4+quad)^(r&7),
  // r&7 == l15&7 (wm,wn,mi*16 all 0 mod 8); ks1 = ks0 ^ 32 (u16).
  const int swz   = (quad ^ (l15 & 7)) * 8;
  const int aOff0 = (wm + l15) * 64 + swz;
  const int bOff0 = (wn + l15) * 64 + swz;

  // staging: unit u, chunk ci = u*512+tid -> row r=ci>>3, slot sc=ci&7 holds
  // source k-chunk sc^(r&7) (source-swizzle, rule #21). Halves: units {0,1}
  // = rows 0-127, {2,3} = rows 128-255.
  const u16* gA[4];
  const u16* gB[4];
#pragma unroll
  for (int i = 0; i < 4; ++i) {
    int ci = i * 512 + tid;
    int r = ci >> 3, sc = ci & 7;
    int col = (sc ^ (r & 7)) * 8;
    gA[i] = A  + (long)(m0 + r) * K + col;
    gB[i] = Bt + (long)(n0 + r) * K + col;
  }

  const int nt = K / BK;            // 16 or 32 here

  // prologue: all 8 units of tile 0, full drain, barrier (proven r4 pattern)
  {
    u16* lA = (u16*)As + tid * 8;
    u16* lB = (u16*)Bs + tid * 8;
    GLD16(gB[0], lB);          GLD16(gB[1], lB + 4096);
    GLD16(gB[2], lB + 8192);   GLD16(gB[3], lB + 12288);
    GLD16(gA[0], lA);          GLD16(gA[1], lA + 4096);
    GLD16(gA[2], lA + 8192);   GLD16(gA[3], lA + 12288);
  }
  SB();
  asm volatile("s_waitcnt vmcnt(0)" ::: "memory");
  SB();
  __builtin_amdgcn_s_barrier();
  SB();
#pragma unroll
  for (int i = 0; i < 4; ++i) { gA[i] += BK; gB[i] += BK; }

  for (int t = 0; t < nt; ++t) {
    const int cur = t & 1;
    const int bo  = cur << 14;                       // cur * 16384 u16 (32 KB)
    const u16* aP0 = (const u16*)As + bo + aOff0;          // ks0 base
    const u16* bP0 = (const u16*)Bs + bo + bOff0;
    const u16* aP1 = (const u16*)As + bo + (aOff0 ^ 32);   // ks1 base
    const u16* bP1 = (const u16*)Bs + bo + (bOff0 ^ 32);
    u16* ldsAn = (u16*)As + (bo ^ 16384) + tid * 8;  // next-buffer dests
    u16* ldsBn = (u16*)Bs + (bo ^ 16384) + tid * 8;
    const bool st1 = (t + 1 < nt);
    bf16x8 bfr0[4], bfr1[4];                         // B: held whole K-tile
    bf16x8 af0[2], af1[2];                           // A: per-phase slice

    // ========== phase 0: rows mi0-1, full K; load ALL B (12 ds_reads) =====
#pragma unroll
    for (int j = 0; j < 2; ++j) {
      af0[j] = *(const bf16x8*)(aP0 + j * 1024);
      af1[j] = *(const bf16x8*)(aP1 + j * 1024);
    }
#pragma unroll
    for (int ni = 0; ni < 4; ++ni) {
      bfr0[ni] = *(const bf16x8*)(bP0 + ni * 1024);
      bfr1[ni] = *(const bf16x8*)(bP1 + ni * 1024);
    }
    if (st1) { GLD16(gB[0], ldsBn); GLD16(gB[1], ldsBn + 4096); }   // Bh0
    SB();
    asm volatile("s_waitcnt lgkmcnt(8)" ::: "memory");   // template hint
    SB();
    __builtin_amdgcn_s_barrier();
    asm volatile("s_waitcnt lgkmcnt(0)" ::: "memory");
    SB();
    __builtin_amdgcn_s_setprio(1);
#pragma unroll
    for (int j = 0; j < 2; ++j)
#pragma unroll
      for (int ni = 0; ni < 4; ++ni)
        acc[j][ni] = __builtin_amdgcn_mfma_f32_16x16x32_bf16(
            bfr0[ni], af0[j], acc[j][ni], 0, 0, 0);   // swapped operands
#pragma unroll
    for (int j = 0; j < 2; ++j)
#pragma unroll
      for (int ni = 0; ni < 4; ++ni)
        acc[j][ni] = __builtin_amdgcn_mfma_f32_16x16x32_bf16(
            bfr1[ni], af1[j], acc[j][ni], 0, 0, 0);
    __builtin_amdgcn_s_setprio(0);
    SB();
    __builtin_amdgcn_s_barrier();
    SB();

    // ========== phase 1: rows mi2-3, full K (4 ds_reads) =====
#pragma unroll
    for (int j = 0; j < 2; ++j) {
      af0[j] = *(const bf16x8*)(aP0 + (2 + j) * 1024);
      af1[j] = *(const bf16x8*)(aP1 + (2 + j) * 1024);
    }
    if (st1) { GLD16(gB[2], ldsBn + 8192); GLD16(gB[3], ldsBn + 12288); } // Bh1
    SB();
    if (st1) asm volatile("s_waitcnt vmcnt(4)" ::: "memory");  // forces Ah1(t)
    else     asm volatile("s_waitcnt vmcnt(0)" ::: "memory");  // final tile
    SB();
    __builtin_amdgcn_s_barrier();
    asm volatile("s_waitcnt lgkmcnt(0)" ::: "memory");
    SB();
    __builtin_amdgcn_s_setprio(1);
#pragma unroll
    for (int j = 0; j < 2; ++j)
#pragma unroll
      for (int ni = 0; ni < 4; ++ni)
        acc[2 + j][ni] = __builtin_amdgcn_mfma_f32_16x16x32_bf16(
            bfr0[ni], af0[j], acc[2 + j][ni], 0, 0, 0);
#pragma unroll
    for (int j = 0; j < 2; ++j)
#pragma unroll
      for (int ni = 0; ni < 4; ++ni)
        acc[2 + j][ni] = __builtin_amdgcn_mfma_f32_16x16x32_bf16(
            bfr1[ni], af1[j], acc[2 + j][ni], 0, 0, 0);
    __builtin_amdgcn_s_setprio(0);
    SB();
    __builtin_amdgcn_s_barrier();
    SB();

    // ========== phase 2: rows mi4-5, full K (4 ds_reads) =====
#pragma unroll
    for (int j = 0; j < 2; ++j) {
      af0[j] = *(const bf16x8*)(aP0 + (4 + j) * 1024);
      af1[j] = *(const bf16x8*)(aP1 + (4 + j) * 1024);
    }
    if (st1) { GLD16(gA[0], ldsAn); GLD16(gA[1], ldsAn + 4096); }   // Ah0
    SB();
    __builtin_amdgcn_s_barrier();
    asm volatile("s_waitcnt lgkmcnt(0)" ::: "memory");
    SB();
    __builtin_amdgcn_s_setprio(1);
#pragma unroll
    for (int j = 0; j < 2; ++j)
#pragma unroll
      for (int ni = 0; ni < 4; ++ni)
        acc[4 + j][ni] = __builtin_amdgcn_mfma_f32_16x16x32_bf16(
            bfr0[ni], af0[j], acc[4 + j][ni], 0, 0, 0);
#pragma unroll
    for (int j = 0; j < 2; ++j)
#pragma unroll
      for (int ni = 0; ni < 4; ++ni)
        acc[4 + j][ni] = __builtin_amdgcn_mfma_f32_16x16x32_bf16(
            bfr1[ni], af1[j], acc[4 + j][ni], 0, 0, 0);
    __builtin_amdgcn_s_setprio(0);
    SB();
    __builtin_amdgcn_s_barrier();
    SB();

    // ========== phase 3: rows mi6-7, full K (4 ds_reads) =====
#pragma unroll
    for (int j = 0; j < 2; ++j) {
      af0[j] = *(const bf16x8*)(aP0 + (6 + j) * 1024);
      af1[j] = *(const bf16x8*)(aP1 + (6 + j) * 1024);
    }
    if (st1) { GLD16(gA[2], ldsAn + 8192); GLD16(gA[3], ldsAn + 12288); } // Ah1
    SB();
    if (st1) asm volatile("s_waitcnt vmcnt(2)" ::: "memory"); // forces B+Ah0(t+1)
    SB();
    __builtin_amdgcn_s_barrier();
    asm volatile("s_waitcnt lgkmcnt(0)" ::: "memory");
    SB();
    __builtin_amdgcn_s_setprio(1);
#pragma unroll
    for (int j = 0; j < 2; ++j)
#pragma unroll
      for (int ni = 0; ni < 4; ++ni)
        acc[6 + j][ni] = __builtin_amdgcn_mfma_f32_16x16x32_bf16(
            bfr0[ni], af0[j], acc[6 + j][ni], 0, 0, 0);
#pragma unroll
    for (int j = 0; j < 2; ++j)
#pragma unroll
      for (int ni = 0; ni < 4; ++ni)
        acc[6 + j][ni] = __builtin_amdgcn_mfma_f32_16x16x32_bf16(
            bfr1[ni], af1[j], acc[6 + j][ni], 0, 0, 0);
    __builtin_amdgcn_s_setprio(0);
    SB();
    __builtin_amdgcn_s_barrier();
    SB();

#pragma unroll
    for (int i = 0; i < 4; ++i) { gA[i] += BK; gB[i] += BK; }
  }

  // epilogue (swapped D layout): row(m) = l15-based, 4 regs = 4 consecutive n-cols
#pragma unroll
  for (int mi = 0; mi < 8; ++mi) {
    const int row = m0 + wm + mi * 16 + l15;      // fixed per lane
    if (MODE == 2) {
      u16* C = (u16*)Call + (long)z * cStride;
      float rs = 0.f;
#pragma unroll
      for (int ni = 0; ni < 4; ++ni) {
        int colb = n0 + wn + ni * 16 + quad * 4;
        floatx4 v = acc[mi][ni];
        float e0 = __expf(v[0] * 0.03125f), e1 = __expf(v[1] * 0.03125f);
        float e2 = __expf(v[2] * 0.03125f), e3 = __expf(v[3] * 0.03125f);
        rs += (e0 + e1) + (e2 + e3);
        uintx2 o;
        o[0] = (unsigned)f2bf(e0) | ((unsigned)f2bf(e1) << 16);
        o[1] = (unsigned)f2bf(e2) | ((unsigned)f2bf(e3) << 16);
        *(uintx2*)(C + (long)row * N + colb) = o;
      }
      rs += __shfl_xor(rs, 16);
      rs += __shfl_xor(rs, 32);
      if (quad == 0) atomicAdd(lsum + (long)z * 2048 + row, rs);
    } else if (MODE == 3) {
      float* C = (float*)Call + (long)z * cStride;
      float inv = 1.0f / lsum[(long)z * 2048 + row];
#pragma unroll
      for (int ni = 0; ni < 4; ++ni) {
        int colb = n0 + wn + ni * 16 + quad * 4;
        floatx4 v = acc[mi][ni];
        floatx4 o = {v[0] * inv, v[1] * inv, v[2] * inv, v[3] * inv};
        *(floatx4*)(C + (long)row * N + colb) = o;
      }
    } else if (MODE == 0) {
#pragma unroll
      for (int ni = 0; ni < 4; ++ni) {
        int colb = n0 + wn + ni * 16 + quad * 4;
        u16* C = (colb < 1024) ? (u16*)Call : (u16*)C2;
        const float* bp = (colb < 1024) ? bias + colb : bias2 + (colb - 1024);
        floatx4 b = *(const floatx4*)bp;
        floatx4 v = acc[mi][ni];
        uintx2 o;
        o[0] = (unsigned)f2bf(v[0] + b[0]) | ((unsigned)f2bf(v[1] + b[1]) << 16);
        o[1] = (unsigned)f2bf(v[2] + b[2]) | ((unsigned)f2bf(v[3] + b[3]) << 16);
        *(uintx2*)(C + (long)row * 1024 + (colb & 1023)) = o;
      }
    } else {  // MODE 1: vT scatter — row=do, cols=4 consecutive t
      u16* C = (u16*)Call;
      float b = bias[row];
#pragma unroll
      for (int ni = 0; ni < 4; ++ni) {
        int colb = n0 + wn + ni * 16 + quad * 4;   // global t index over B*T
        long base = ((long)(colb >> 11) * 1024) * 2048 + (colb & 2047);
        floatx4 v = acc[mi][ni];
        uintx2 o;
        o[0] = (unsigned)f2bf(v[0] + b) | ((unsigned)f2bf(v[1] + b) << 16);
        o[1] = (unsigned)f2bf(v[2] + b) | ((unsigned)f2bf(v[3] + b) << 16);
        *(uintx2*)(C + base + (long)row * 2048) = o;
      }
    }
  }
}

// ---------------------------------------------------------------------------
extern "C" void kernel_launch(void* const* d_in, const int* in_sizes, int n_in,
                              void* d_out, int out_size, void* d_ws, size_t ws_size,
                              hipStream_t stream) {
  const float* x  = (const float*)d_in[0];
  const float* Wq = (const float*)d_in[1];
  const float* bq = (const float*)d_in[2];
  const float* Wk = (const float*)d_in[3];
  const float* bk = (const float*)d_in[4];
  const float* Wv = (const float*)d_in[5];
  const float* bv = (const float*)d_in[6];
  float* out = (float*)d_out;

  const long BT = 16384;   // B*T
  u16* xb = (u16*)d_ws;                    // [16384,1024] bf16   32 MB
  u16* WT = xb + BT * 1024;                // [3][1024,1024]       6 MB
  u16* qb = WT + 3L * 1024 * 1024;         // [16384,1024]        32 MB
  u16* kb = qb + BT * 1024;                // [16384,1024]        32 MB
  u16* vT = kb + BT * 1024;                // [8][1024][2048]     32 MB
  u16* S  = vT + BT * 1024;                // [8][2048][2048]     64 MB
  float* lsum = (float*)(S + 8L * 2048 * 2048);   // [8][2048]    64 KB

  hipMemsetAsync(lsum, 0, 8 * 2048 * sizeof(float), stream);

  // z 0..2: transpose-cast W; z 3..10: cast x
  prep_kernel<<<dim3(32, 32, 11), dim3(32, 8), 0, stream>>>(x, Wq, Wk, Wv, xb, WT);

  // q|k = x [Wq|Wk] + [bq|bk]   (WT rows 0..2047 are Wq^T then Wk^T)
  gemm_bt<0, 8><<<dim3(8, 64, 1), 512, 0, stream>>>(
      xb, WT, qb, kb, bq, bk, nullptr, 16384, 2048, 1024, 0, 0, 0);
  // vT[b][do][t] = (Wv^T x^T + bv) : A=WvT [1024,1024], Bt=xb [16384,1024]
  gemm_bt<1, 8><<<dim3(64, 4, 1), 512, 0, stream>>>(
      WT + 2L * 1024 * 1024, xb, vT, nullptr, bv, nullptr, nullptr,
      1024, 16384, 1024, 0, 0, 0);
  // E[b] = exp(q_b k_b^T / 32), row-sums -> lsum
  gemm_bt<2, 8><<<dim3(8, 8, 8), 512, 0, stream>>>(
      qb, kb, S, nullptr, nullptr, nullptr, lsum,
      2048, 2048, 1024, 2048L * 1024, 2048L * 1024, 2048L * 2048);
  // out[b] = (E_b V_b) / lsum : A=E [2048,2048], Bt=vT_b [1024,2048]
  gemm_bt<3, 4><<<dim3(4, 8, 8), 512, 0, stream>>>(
      S, vT, out, nullptr, nullptr, nullptr, lsum,
      2048, 1024, 2048, 2048L * 2048, 1024L * 2048, 2048L * 1024);
}